// Round 6
// baseline (40.001 us; speedup 1.0000x reference)
//
#include <hip/hip_runtime.h>

// Locally-connected 2D conv via MFMA (bf16 inputs, fp32 accumulate).
// x:(8,32,64,64)  weights:(64,64,32,32,3,3)  bias:(32)  out:(8,32,64,64)
// out[b,o,i,j] = bias[o] + sum_k xpatch[b,k] * W[loc][o][k],  k=c*9+a*3+bb,
//   xpatch[b,k] = x[b, c, i+bb-1, j+a-1]   (a=col offset, bb=row offset)
//
// R5: one wave per 2 locations; 512 WGs x 256thr (2 WGs/CU, zero tail).
// Per loc: out[8b x 32o] = X[8 x 288] * W^T -> mfma_f32_16x16x32_bf16,
// 2 o-tiles x 9 k-steps (M=16 half-used; compute is ~30x under the stream).
// Weights: global->reg float4 batches (18/batch = o-tile), cvt->bf16,
// rotation prefetch (R4-style) so >=1 batch always in flight; raw
// lgkm-only barriers never drain vmcnt. x: coalesced xnat slab -> bf16
// A-fragments in LDS (built once per WG, 9 ds_read_b128 per loc).

#define NB 8
#define NC 32
#define NO 32
#define NH 64
#define NW 64
#define KK 288
#define LOCS 8
#define XCOLS 10                       // j0-1 .. j0+8
#define XNAT_SZ (NB * NC * 3 * XCOLS)  // 7680 floats

typedef __attribute__((ext_vector_type(8))) short s16x8;
typedef __attribute__((ext_vector_type(4))) float f32x4;

union Frag {
  unsigned int u[4];
  unsigned short s[8];
  uint4 q;
  s16x8 v;
};

__device__ __forceinline__ unsigned short f2bf(float f) {
  unsigned int u = __float_as_uint(f);
  u += 0x7FFFu + ((u >> 16) & 1u);     // RNE
  return (unsigned short)(u >> 16);
}

__global__ __launch_bounds__(256, 2) void lc2d_kernel(
    const float* __restrict__ x, const float* __restrict__ w,
    const float* __restrict__ bias, float* __restrict__ out) {
  const int bid = blockIdx.x;                  // 0..511
  const int g = (bid & 7) * 64 + (bid >> 3);   // XCD-cluster (bijective)
  const int loc0 = g * LOCS;
  const int i = loc0 >> 6;                     // 8 | 64 -> same i per WG
  const int j0 = loc0 & 63;
  const int t = threadIdx.x;
  const int lane = t & 63;
  const int wv = t >> 6;                       // wave 0..3
  const int m16 = lane & 15;
  const int kg = lane >> 4;                    // k-group 0..3

  __shared__ float xnat[XNAT_SZ];              // 30720 B
  __shared__ unsigned int xtb[LOCS * 9 * 32 * 4];  // A-frags bf16, 36864 B
  __shared__ float obuf[LOCS * NB * NO];       // 8192 B

  // ---- coalesced x stage: row=(b,c,yy), cols cc=0..9 -> xc=j0-1+cc ----
#pragma unroll
  for (int it = 0; it < 30; ++it) {
    int e = t + it * 256;
    int row = e / XCOLS;
    int cc = e - row * XCOLS;
    int bc = row / 3;                          // b*32 + c
    int yy = row - bc * 3;
    int y = i + yy - 1;
    int xc = j0 + cc - 1;
    float v = 0.f;
    if ((unsigned)y < 64u && (unsigned)xc < 64u)
      v = x[(bc * NH + y) * NW + xc];
    xnat[e] = v;
  }
  asm volatile("" ::: "memory");  // keep weight loads after stage loads

  // ---- issue this wave's first two weight batches (locA, o-tiles 0,1) ----
  float4 wb[2][18];
  {
    const int lloc = 2 * wv;
    const float* wp0 = w + (((size_t)(loc0 + lloc) * NO) + 0 * 16 + m16) * KK + kg * 8;
    const float* wp1 = w + (((size_t)(loc0 + lloc) * NO) + 1 * 16 + m16) * KK + kg * 8;
#pragma unroll
    for (int ks = 0; ks < 9; ++ks) {
      wb[0][2 * ks]     = *(const float4*)(wp0 + ks * 32);
      wb[0][2 * ks + 1] = *(const float4*)(wp0 + ks * 32 + 4);
      wb[1][2 * ks]     = *(const float4*)(wp1 + ks * 32);
      wb[1][2 * ks + 1] = *(const float4*)(wp1 + ks * 32 + 4);
    }
  }
  asm volatile("s_waitcnt lgkmcnt(0)\n\ts_barrier" ::: "memory");

  // ---- build bf16 A-fragments: slot (loc, ks, kg*8+m) = 8 bf16 (16 B) ----
  // A[row=m][k=ks*32+kg*8+e] = xpatch(b=m, k, loc)
  {
    const int bl = t >> 5;                     // loc 0..7
    const int idx = t & 31;                    // kg*8 + m
    const int bkg = idx >> 3;
    const int bm = idx & 7;
#pragma unroll
    for (int ks = 0; ks < 9; ++ks) {
      Frag f;
#pragma unroll
      for (int e = 0; e < 8; ++e) {
        int k = ks * 32 + bkg * 8 + e;
        int c = k / 9;
        int rem = k - c * 9;
        int a = rem / 3;                       // col offset
        int bb = rem - a * 3;                  // row offset
        f.s[e] = f2bf(xnat[((bm * NC + c) * 3 + bb) * XCOLS + bl + a]);
      }
      *(uint4*)&xtb[((bl * 9 + ks) * 32 + idx) * 4] = f.q;
    }
  }
  asm volatile("s_waitcnt lgkmcnt(0)\n\ts_barrier" ::: "memory");

  // ---- compute: 4 phases (locA/locB x o-tile 0/1), 9 MFMA each ----
  uint4 afr[9];
  auto load_a = [&](int lloc) {
#pragma unroll
    for (int ks = 0; ks < 9; ++ks) {
      if (m16 < 8)
        afr[ks] = *(const uint4*)&xtb[((lloc * 9 + ks) * 32 + kg * 8 + m16) * 4];
      else
        afr[ks] = make_uint4(0, 0, 0, 0);
    }
  };

#pragma unroll
  for (int p = 0; p < 4; ++p) {
    const int lp = p >> 1;
    const int ot = p & 1;
    const int lloc = 2 * wv + lp;
    if (ot == 0) load_a(lloc);

    const int nlloc = 2 * wv + 1;              // phases 2,3: locB, ot = p
    const float* wpn = w + (((size_t)(loc0 + nlloc) * NO) + p * 16 + m16) * KK + kg * 8;

    f32x4 acc = {0.f, 0.f, 0.f, 0.f};
#pragma unroll
    for (int ks = 0; ks < 9; ++ks) {
      float4 lo = wb[p & 1][2 * ks];
      float4 hi = wb[p & 1][2 * ks + 1];
      Frag fb;
      fb.s[0] = f2bf(lo.x); fb.s[1] = f2bf(lo.y);
      fb.s[2] = f2bf(lo.z); fb.s[3] = f2bf(lo.w);
      fb.s[4] = f2bf(hi.x); fb.s[5] = f2bf(hi.y);
      fb.s[6] = f2bf(hi.z); fb.s[7] = f2bf(hi.w);
      Frag fa; fa.q = afr[ks];
      acc = __builtin_amdgcn_mfma_f32_16x16x32_bf16(fa.v, fb.v, acc, 0, 0, 0);
      if (p < 2) {                             // rotate in batch p+2
        wb[p & 1][2 * ks]     = *(const float4*)(wpn + ks * 32);
        wb[p & 1][2 * ks + 1] = *(const float4*)(wpn + ks * 32 + 4);
      }
    }

    // D: lane holds rows (kg*4+r), col = m16 (o within tile); rows>=8 unused
    if (kg < 2) {
#pragma unroll
      for (int r = 0; r < 4; ++r) {
        int row = kg * 4 + r;                  // = b
        obuf[(lloc * NB + row) * NO + ot * 16 + m16] = acc[r];
      }
    }
  }
  asm volatile("s_waitcnt lgkmcnt(0)\n\ts_barrier" ::: "memory");

  // ---- final store: thread t = (b,o); out[b,o,i,j0..j0+7] ----
  {
    const int fb_ = t >> 5;                    // b
    const int fo = t & 31;                     // o
    const float bia = bias[fo];
    float4 r0, r1;
    r0.x = obuf[(0 * NB + fb_) * NO + fo] + bia;
    r0.y = obuf[(1 * NB + fb_) * NO + fo] + bia;
    r0.z = obuf[(2 * NB + fb_) * NO + fo] + bia;
    r0.w = obuf[(3 * NB + fb_) * NO + fo] + bia;
    r1.x = obuf[(4 * NB + fb_) * NO + fo] + bia;
    r1.y = obuf[(5 * NB + fb_) * NO + fo] + bia;
    r1.z = obuf[(6 * NB + fb_) * NO + fo] + bia;
    r1.w = obuf[(7 * NB + fb_) * NO + fo] + bia;
    float* op = &out[((size_t)(fb_ * NO + fo) * NH + i) * NW + j0];
    *(float4*)op = r0;
    *(float4*)(op + 4) = r1;
  }
}

extern "C" void kernel_launch(void* const* d_in, const int* in_sizes, int n_in,
                              void* d_out, int out_size, void* d_ws, size_t ws_size,
                              hipStream_t stream) {
  const float* x    = (const float*)d_in[0];
  const float* w    = (const float*)d_in[1];
  const float* bias = (const float*)d_in[2];
  float* out = (float*)d_out;
  lc2d_kernel<<<dim3(NH * NW / LOCS), dim3(256), 0, stream>>>(x, w, bias, out);
}

// Round 7
// 33.834 us; speedup vs baseline: 1.1823x; 1.1823x over previous
//
#include <hip/hip_runtime.h>
#include <hip/hip_bf16.h>

// Locally-connected 2D conv via MFMA (bf16 inputs, fp32 accumulate).
// x:(8,32,64,64)  weights:(64,64,32,32,3,3)  bias:(32)  out:(8,32,64,64)
// out[b,o,i,j] = bias[o] + sum_k xpatch[b,k] * W[loc][o][k],  k=c*9+a*3+bb,
//   xpatch[b,k] = x[b, c, i+bb-1, j+a-1]   (a=col offset, bb=row offset)
//
// R6: one wave per (loc, o-tile) phase. 2048 WGs x 256thr, LOCS=2 per WG,
// 4 WGs/CU (16 waves). Per wave: issue 12 x-stage + 18 weight dwordx4 up
// front (weights stay in flight through stage+frag-build; in-order vmcnt
// means stage consumption leaves all 18 pending), then 9 MFMA consuming
// weights as they land (HW v_cvt bf16 via __float2bfloat16 — R5's software
// RNE was the VALU hog). No per-loc rotation, no vmcnt-draining barriers:
// 3 raw lgkm-only barriers per WG total. Numerics verified in R5
// (absmax 4.9e-4 vs threshold 2.29e-3).

#define NB 8
#define NC 32
#define NO 32
#define NH 64
#define NW 64
#define KK 288
#define LOCS 2
#define XCOLS 4                        // j0-1 .. j0+2
#define NROWS (NB * NC * 3)            // 768
#define XNAT_SZ (NROWS * XCOLS)        // 3072 floats
#define NSLOT (LOCS * 9 * 32)          // 576 A-frag slots (16 B each)

typedef __attribute__((ext_vector_type(8))) short s16x8;
typedef __attribute__((ext_vector_type(4))) float f32x4;

union Frag { unsigned short s[8]; uint4 q; s16x8 v; };

__device__ __forceinline__ unsigned short f2bf(float f) {
  __hip_bfloat16 h = __float2bfloat16(f);   // HW cvt (RNE) on gfx950
  return *reinterpret_cast<unsigned short*>(&h);
}

__global__ __launch_bounds__(256, 4) void lc2d_kernel(
    const float* __restrict__ x, const float* __restrict__ w,
    const float* __restrict__ bias, float* __restrict__ out) {
  const int bid = blockIdx.x;                    // 0..2047
  const int g = (bid & 7) * 256 + (bid >> 3);    // XCD-bijective cluster
  const int loc0 = g * LOCS;
  const int i = loc0 >> 6;                       // 2 | 64 -> same i per WG
  const int j0 = loc0 & 63;
  const int t = threadIdx.x;
  const int lane = t & 63;
  const int wv = t >> 6;                         // wave 0..3
  const int m16 = lane & 15;
  const int kg = lane >> 4;                      // k-group 0..3
  const int l = wv >> 1;                         // this wave's loc (0/1)
  const int ot = wv & 1;                         // this wave's o-tile (0/1)

  __shared__ float xnat[XNAT_SZ];                // 12288 B
  __shared__ uint4 xtb[NSLOT];                   //  9216 B  (bf16 A-frags)
  __shared__ float obuf[LOCS][NB][NO];           //  2048 B

  // ---- 1. x-stage loads into regs (issued first; oldest in vmcnt) ----
  float sv[12];
#pragma unroll
  for (int it = 0; it < 12; ++it) {
    int e = t + it * 256;
    int row = e >> 2;                  // (b*32+c)*3 + yy
    int cc = e & 3;
    int bc = row / 3;
    int yy = row - bc * 3;
    int y = i + yy - 1;
    int xc = j0 + cc - 1;
    float v = 0.f;
    if ((unsigned)y < 64u && (unsigned)xc < 64u)
      v = x[(bc * NH + y) * NW + xc];
    sv[it] = v;
  }

  // ---- 2. weight loads: 18 dwordx4, in flight until the MFMA loop ----
  // lane (m16 = o-in-tile, kg = k-chunk): W[o][ks*32 + kg*8 + 0..7]
  float4 wf[18];
  {
    const float* wp =
        w + ((size_t)(loc0 + l) * NO + ot * 16 + m16) * KK + kg * 8;
#pragma unroll
    for (int ks = 0; ks < 9; ++ks) {
      wf[2 * ks]     = *(const float4*)(wp + ks * 32);
      wf[2 * ks + 1] = *(const float4*)(wp + ks * 32 + 4);
    }
  }

  // ---- 3. publish xnat (ds_writes wait only the stage loads: vmcnt(18)) ----
#pragma unroll
  for (int it = 0; it < 12; ++it) xnat[t + it * 256] = sv[it];
  asm volatile("s_waitcnt lgkmcnt(0)\n\ts_barrier" ::: "memory");

  // ---- 4. build bf16 A-frags: slot (l2, ks, kg*8+b) = 8 bf16 of row b ----
  for (int sid = t; sid < NSLOT; sid += 256) {
    int l2 = sid / 288;                // 9*32 slots per loc
    int r = sid - l2 * 288;
    int ks = r >> 5;
    int idx = r & 31;
    int bkg = idx >> 3;
    int bm = idx & 7;
    Frag f;
#pragma unroll
    for (int e = 0; e < 8; ++e) {
      int k = ks * 32 + bkg * 8 + e;
      int c = k / 9;
      int rem = k - c * 9;
      int a = rem / 3;                 // col offset (W axis)
      int bb = rem - a * 3;            // row offset (H axis)
      f.s[e] = f2bf(xnat[((bm * NC + c) * 3 + bb) * XCOLS + l2 + a]);
    }
    xtb[sid] = f.q;
  }
  asm volatile("s_waitcnt lgkmcnt(0)\n\ts_barrier" ::: "memory");

  // ---- 5. A-frags (rows 8-15 duplicate 0-7; D rows 8-15 discarded) ----
  uint4 afr[9];
#pragma unroll
  for (int ks = 0; ks < 9; ++ks)
    afr[ks] = xtb[(l * 9 + ks) * 32 + kg * 8 + (m16 & 7)];

  // ---- 6. cvt weights as they land + 9 MFMA ----
  f32x4 acc = {0.f, 0.f, 0.f, 0.f};
#pragma unroll
  for (int ks = 0; ks < 9; ++ks) {
    float4 lo = wf[2 * ks], hi = wf[2 * ks + 1];
    Frag fb;
    fb.s[0] = f2bf(lo.x); fb.s[1] = f2bf(lo.y);
    fb.s[2] = f2bf(lo.z); fb.s[3] = f2bf(lo.w);
    fb.s[4] = f2bf(hi.x); fb.s[5] = f2bf(hi.y);
    fb.s[6] = f2bf(hi.z); fb.s[7] = f2bf(hi.w);
    Frag fa; fa.q = afr[ks];
    acc = __builtin_amdgcn_mfma_f32_16x16x32_bf16(fa.v, fb.v, acc, 0, 0, 0);
  }

  // ---- D: row = kg*4 + r = b, col = m16 = o-in-tile ----
  if (kg < 2) {
#pragma unroll
    for (int r = 0; r < 4; ++r)
      obuf[l][kg * 4 + r][ot * 16 + m16] = acc[r];
  }
  asm volatile("s_waitcnt lgkmcnt(0)\n\ts_barrier" ::: "memory");

  // ---- 7. final store: thread t = (b,o); out[b,o,i,j0..j0+1] ----
  {
    const int b_ = t >> 5;
    const int o_ = t & 31;
    const float bia = bias[o_];
    float2 r2;
    r2.x = obuf[0][b_][o_] + bia;
    r2.y = obuf[1][b_][o_] + bia;
    *reinterpret_cast<float2*>(
        &out[((size_t)(b_ * NO + o_) * NH + i) * NW + j0]) = r2;
  }
}

extern "C" void kernel_launch(void* const* d_in, const int* in_sizes, int n_in,
                              void* d_out, int out_size, void* d_ws, size_t ws_size,
                              hipStream_t stream) {
  const float* x    = (const float*)d_in[0];
  const float* w    = (const float*)d_in[1];
  const float* bias = (const float*)d_in[2];
  float* out = (float*)d_out;
  lc2d_kernel<<<dim3(NH * NW / LOCS), dim3(256), 0, stream>>>(x, w, bias, out);
}